// Round 5
// baseline (734.279 us; speedup 1.0000x reference)
//
#include <hip/hip_runtime.h>
#include <hip/hip_bf16.h>
#include <stdint.h>

// Problem constants (reference: T=10, N=2048, E=32768, H=256)
#define TT 10
#define NN 2048
#define EE 32768
#define HH 256

typedef short bf16x8 __attribute__((ext_vector_type(8)));
typedef float f32x4 __attribute__((ext_vector_type(4)));

__device__ __forceinline__ float b2f(unsigned short u) {
    unsigned int x = ((unsigned int)u) << 16;
    return __builtin_bit_cast(float, x);
}
__device__ __forceinline__ unsigned short f2b(float f) {
    unsigned int x = __builtin_bit_cast(unsigned int, f);
    unsigned int r = x + 0x7FFFu + ((x >> 16) & 1u);
    return (unsigned short)(r >> 16);
}

#define GLOAD_LDS16(g, l)                                                      \
    __builtin_amdgcn_global_load_lds(                                          \
        (const __attribute__((address_space(1))) void*)(g),                    \
        (__attribute__((address_space(3))) void*)(l), 16, 0, 0)

// ---------------- setup kernels ----------------

__global__ void cvt_bf16_kernel(const float* __restrict__ in,
                                unsigned short* __restrict__ out, int n) {
    int i = blockIdx.x * blockDim.x + threadIdx.x;
    int stride = gridDim.x * blockDim.x;
    for (; i < n; i += stride) out[i] = f2b(in[i]);
}

// W: [K][256] row-major -> Wt: [256][KPAD] bf16, zero-padded
__global__ void transpose_w_kernel(const float* __restrict__ W,
                                   unsigned short* __restrict__ Wt, int K, int KPAD) {
    int idx = blockIdx.x * blockDim.x + threadIdx.x;
    if (idx >= 256 * KPAD) return;
    int n = idx / KPAD, k = idx - n * KPAD;
    Wt[idx] = (k < K) ? f2b(W[k * 256 + n]) : (unsigned short)0;
}

__global__ void zero_f32_kernel(float* __restrict__ p, int n) {
    int i = blockIdx.x * blockDim.x + threadIdx.x;
    int stride = gridDim.x * blockDim.x;
    for (; i < n; i += stride) p[i] = 0.0f;
}

__global__ void count_kernel(const int* __restrict__ rows, int* __restrict__ counts) {
    int e = blockIdx.x * blockDim.x + threadIdx.x;
    if (e < EE) atomicAdd(&counts[rows[e]], 1);
}

// ---------------- radial (full batch) ----------------
// 16 lanes per edge-instance el = t*EE+e: radial32[el][0..15]=normalized gram,
// [16..31]=0; cdiff[el][12] = x[t,row]-x[t,col].
__global__ __launch_bounds__(256) void radial_kernel(
    const float* __restrict__ x, const int* __restrict__ rows,
    const int* __restrict__ cols, unsigned short* __restrict__ radial32,
    float* __restrict__ cdiff) {
    int tid = threadIdx.x;
    int el = blockIdx.x * 16 + (tid >> 4);
    int l16 = tid & 15;
    int e = el & (EE - 1);
    int t = el >> 15;
    const float* xt = x + (size_t)t * NN * 12;
    int r = rows[e], c = cols[e];

    int j = l16 >> 2, kk = l16 & 3;
    float g = 0.f;
    for (int d = 0; d < 3; ++d) {
        float a = xt[r * 12 + j * 3 + d] - xt[c * 12 + j * 3 + d];
        float b = xt[r * 12 + kk * 3 + d] - xt[c * 12 + kk * 3 + d];
        g += a * b;
    }
    float ss = g * g;
    ss += __shfl_xor(ss, 1);
    ss += __shfl_xor(ss, 2);
    ss += __shfl_xor(ss, 4);
    ss += __shfl_xor(ss, 8);
    float denom = fmaxf(sqrtf(ss), 1e-12f);
    radial32[(size_t)el * 32 + l16] = f2b(g / denom);
    radial32[(size_t)el * 32 + 16 + l16] = 0;
    if (l16 < 12) {
        cdiff[(size_t)el * 12 + l16] = xt[r * 12 + l16] - xt[c * 12 + l16];
    }
}

// ---------------- GEMM1: Y1 = relu([h[row]|h[col]|radial] @ We1t^T + be1) ----------------
// m97 structure: 128x128 tile, BK=32, 4 waves (2x2), wave = 64x64 (4x4 frags).
__global__ __launch_bounds__(256) void gemm1_kernel(
    const unsigned short* __restrict__ hb, const unsigned short* __restrict__ radial32,
    const unsigned short* __restrict__ We1t, const float* __restrict__ be1,
    const int* __restrict__ rows, const int* __restrict__ cols,
    unsigned short* __restrict__ Y1) {
    const int KPAD = 576;
    __shared__ unsigned short As[128 * 32];
    __shared__ unsigned short Bs[128 * 32];
    int tid = threadIdx.x;
    int lane = tid & 63, w = tid >> 6;
    int wr = w >> 1, wc = w & 1;
    int blockRow = blockIdx.x * 128, colBase = blockIdx.y * 128;
    int l4 = lane >> 2;
    int seg = lane & 3;

    int ar0 = blockRow + w * 16 + l4;
    int ar1 = ar0 + 64;
    int br0 = colBase + w * 16 + l4;
    int br1 = br0 + 64;

    const unsigned short* pB0 = We1t + (size_t)br0 * KPAD + seg * 8;
    const unsigned short* pB1 = We1t + (size_t)br1 * KPAD + seg * 8;

    int e0 = ar0 & (EE - 1), t0 = ar0 >> 15;
    int e1 = ar1 & (EE - 1), t1 = ar1 >> 15;
    const unsigned short* hr0 = hb + ((size_t)(t0 << 11) + rows[e0]) * 256 + seg * 8;
    const unsigned short* hc0 = hb + ((size_t)(t0 << 11) + cols[e0]) * 256 + seg * 8 - 256;
    const unsigned short* rd0 = radial32 + (size_t)ar0 * 32 + seg * 8 - 512;
    const unsigned short* hr1 = hb + ((size_t)(t1 << 11) + rows[e1]) * 256 + seg * 8;
    const unsigned short* hc1 = hb + ((size_t)(t1 << 11) + cols[e1]) * 256 + seg * 8 - 256;
    const unsigned short* rd1 = radial32 + (size_t)ar1 * 32 + seg * 8 - 512;

    unsigned short* ldsA = As + w * 512;
    unsigned short* ldsB = Bs + w * 512;

    f32x4 acc[4][4] = {};
    int lr = lane & 15, lq = lane >> 4;

    for (int k0 = 0; k0 < KPAD; k0 += 32) {
        const unsigned short* s0 = (k0 < 256) ? hr0 + k0 : (k0 < 512) ? hc0 + k0 : rd0 + k0;
        const unsigned short* s1 = (k0 < 256) ? hr1 + k0 : (k0 < 512) ? hc1 + k0 : rd1 + k0;
        GLOAD_LDS16(s0, ldsA);
        GLOAD_LDS16(s1, ldsA + 2048);
        GLOAD_LDS16(pB0 + k0, ldsB);
        GLOAD_LDS16(pB1 + k0, ldsB + 2048);
        __syncthreads();
        bf16x8 a[4], b[4];
#pragma unroll
        for (int m = 0; m < 4; ++m)
            a[m] = *reinterpret_cast<const bf16x8*>(
                As + (wr * 64 + m * 16 + lr) * 32 + lq * 8);
#pragma unroll
        for (int n = 0; n < 4; ++n)
            b[n] = *reinterpret_cast<const bf16x8*>(
                Bs + (wc * 64 + n * 16 + lr) * 32 + lq * 8);
#pragma unroll
        for (int m = 0; m < 4; ++m)
#pragma unroll
            for (int n = 0; n < 4; ++n)
                acc[m][n] = __builtin_amdgcn_mfma_f32_16x16x32_bf16(
                    a[m], b[n], acc[m][n], 0, 0, 0);
        __syncthreads();
    }

    float bv[4];
#pragma unroll
    for (int n = 0; n < 4; ++n) bv[n] = be1[colBase + wc * 64 + n * 16 + lr];

#pragma unroll
    for (int m = 0; m < 4; ++m)
#pragma unroll
        for (int r = 0; r < 4; ++r) {
            int row = blockRow + wr * 64 + m * 16 + lq * 4 + r;
#pragma unroll
            for (int n = 0; n < 4; ++n) {
                int col = colBase + wc * 64 + n * 16 + lr;
                Y1[(size_t)row * 256 + col] = f2b(fmaxf(acc[m][n][r] + bv[n], 0.f));
            }
        }
}

// ---------------- fused tail: GEMM2 (+agg atomics) -> Es -> GEMM3 -> m -> csum ----------------
// 512 threads = 8 waves (2 row-waves x 4 col-waves); block = 128 edge rows x 256 cols.
__global__ __launch_bounds__(512) void edge_tail_kernel(
    const unsigned short* __restrict__ Y1, const unsigned short* __restrict__ We2t,
    const float* __restrict__ be2, const unsigned short* __restrict__ Wc1t,
    const float* __restrict__ bc1, const float* __restrict__ Wc2,
    const int* __restrict__ rows, const float* __restrict__ cdiff,
    float* __restrict__ aggf, float* __restrict__ csum) {
    __shared__ unsigned short As[128 * 32];   // 8 KB
    __shared__ unsigned short Bs[256 * 32];   // 16 KB
    __shared__ unsigned short Es[128 * 256];  // 64 KB (XOR-swizzled)
    __shared__ float Ms[128][4];              // 2 KB

    int tid = threadIdx.x;
    int lane = tid & 63, w = tid >> 6;
    int wr = w >> 2, wc = w & 3;
    int lr = lane & 15, lq = lane >> 4;
    int blockRow = blockIdx.x * 128;
    int tt = blockRow >> 15;

    // staging pointers: A row = tid>>2 (0..127), seg = tid&3; B rows tid>>2 and +128
    int arow = tid >> 2, aseg = tid & 3;
    const unsigned short* pA = Y1 + (size_t)(blockRow + arow) * 256 + aseg * 8;
    const unsigned short* pB20 = We2t + (size_t)arow * 256 + aseg * 8;
    const unsigned short* pB21 = We2t + (size_t)(128 + arow) * 256 + aseg * 8;
    const unsigned short* pC0 = Wc1t + (size_t)arow * 256 + aseg * 8;
    const unsigned short* pC1 = Wc1t + (size_t)(128 + arow) * 256 + aseg * 8;

    unsigned short* ldsA = As + w * 512;   // wave-uniform bases (+ lane*16B implicit)
    unsigned short* ldsB0 = Bs + w * 512;
    unsigned short* ldsB1 = Bs + 4096 + w * 512;

    f32x4 acc[4][4] = {};

    // ---- GEMM2: E2 = relu(Y1 @ We2t^T + be2), K=256 ----
    for (int k0 = 0; k0 < 256; k0 += 32) {
        GLOAD_LDS16(pA + k0, ldsA);
        GLOAD_LDS16(pB20 + k0, ldsB0);
        GLOAD_LDS16(pB21 + k0, ldsB1);
        __syncthreads();
        bf16x8 a[4], b[4];
#pragma unroll
        for (int m = 0; m < 4; ++m)
            a[m] = *reinterpret_cast<const bf16x8*>(
                As + (wr * 64 + m * 16 + lr) * 32 + lq * 8);
#pragma unroll
        for (int n = 0; n < 4; ++n)
            b[n] = *reinterpret_cast<const bf16x8*>(
                Bs + (wc * 64 + n * 16 + lr) * 32 + lq * 8);
#pragma unroll
        for (int m = 0; m < 4; ++m)
#pragma unroll
            for (int n = 0; n < 4; ++n)
                acc[m][n] = __builtin_amdgcn_mfma_f32_16x16x32_bf16(
                    a[m], b[n], acc[m][n], 0, 0, 0);
        __syncthreads();
    }
    {   // epilogue: agg atomics (interleaved, round-3-proven) + swizzled Es write
        float bv[4];
#pragma unroll
        for (int n = 0; n < 4; ++n) bv[n] = be2[wc * 64 + n * 16 + lr];
#pragma unroll
        for (int m = 0; m < 4; ++m)
#pragma unroll
            for (int r = 0; r < 4; ++r) {
                int rl = wr * 64 + m * 16 + lq * 4 + r;
                int node = tt * NN + rows[(blockRow + rl) & (EE - 1)];
                int xsw = (rl & 7) << 3;
#pragma unroll
                for (int n = 0; n < 4; ++n) {
                    int col = wc * 64 + n * 16 + lr;
                    float v = fmaxf(acc[m][n][r] + bv[n], 0.f);
                    Es[rl * 256 + (col ^ xsw)] = f2b(v);
                    atomicAdd(&aggf[(size_t)node * 256 + col], v);
                }
            }
    }
    __syncthreads();

    // ---- GEMM3: Y3 = relu(E2 @ Wc1t^T + bc1), K=256, A from swizzled Es ----
#pragma unroll
    for (int m = 0; m < 4; ++m)
#pragma unroll
        for (int n = 0; n < 4; ++n) acc[m][n] = (f32x4){0.f, 0.f, 0.f, 0.f};
    for (int k0 = 0; k0 < 256; k0 += 32) {
        GLOAD_LDS16(pC0 + k0, ldsB0);
        GLOAD_LDS16(pC1 + k0, ldsB1);
        __syncthreads();
        bf16x8 a[4], b[4];
        int xsr = (lr & 7) << 3;
#pragma unroll
        for (int m = 0; m < 4; ++m)
            a[m] = *reinterpret_cast<const bf16x8*>(
                Es + (wr * 64 + m * 16 + lr) * 256 + ((k0 + lq * 8) ^ xsr));
#pragma unroll
        for (int n = 0; n < 4; ++n)
            b[n] = *reinterpret_cast<const bf16x8*>(
                Bs + (wc * 64 + n * 16 + lr) * 32 + lq * 8);
#pragma unroll
        for (int m = 0; m < 4; ++m)
#pragma unroll
            for (int n = 0; n < 4; ++n)
                acc[m][n] = __builtin_amdgcn_mfma_f32_16x16x32_bf16(
                    a[m], b[n], acc[m][n], 0, 0, 0);
        __syncthreads();
    }
    {   // epilogue: m = relu(.)+bc1 dot Wc2, 16-lane reduce, cross-wave via Ms
        float bv[4], wv[4];
#pragma unroll
        for (int n = 0; n < 4; ++n) {
            int col = wc * 64 + n * 16 + lr;
            bv[n] = bc1[col];
            wv[n] = Wc2[col];
        }
#pragma unroll
        for (int m = 0; m < 4; ++m)
#pragma unroll
            for (int r = 0; r < 4; ++r) {
                float p = 0.f;
#pragma unroll
                for (int n = 0; n < 4; ++n)
                    p += fmaxf(acc[m][n][r] + bv[n], 0.f) * wv[n];
                p += __shfl_xor(p, 1);
                p += __shfl_xor(p, 2);
                p += __shfl_xor(p, 4);
                p += __shfl_xor(p, 8);
                if (lr == 0) Ms[wr * 64 + m * 16 + lq * 4 + r][wc] = p;
            }
    }
    __syncthreads();

    // ---- coord scatter: csum[node][i] += cdiff[el][i] * m ----
    if (tid < 128) {
        float mval = Ms[tid][0] + Ms[tid][1] + Ms[tid][2] + Ms[tid][3];
        int grow = blockRow + tid;
        int node = tt * NN + rows[grow & (EE - 1)];
#pragma unroll
        for (int i = 0; i < 12; ++i)
            atomicAdd(&csum[(size_t)node * 12 + i],
                      cdiff[(size_t)grow * 12 + i] * mval);
    }
}

// ---------------- node GEMM (128x128, BK=32) ----------------
// EPI 0: relu -> bf16 store.  EPI 2: f32 store outf = acc + bias + resid.
template<int EPI>
__global__ __launch_bounds__(256) void node_gemm_kernel(
    const unsigned short* __restrict__ A, const unsigned short* __restrict__ Wt,
    const float* __restrict__ bias, unsigned short* __restrict__ Cb, int KPAD,
    const float* __restrict__ resid, float* __restrict__ outf) {
    __shared__ unsigned short As[128 * 32];
    __shared__ unsigned short Bs[128 * 32];
    int tid = threadIdx.x;
    int lane = tid & 63, w = tid >> 6;
    int wr = w >> 1, wc = w & 1;
    int blockRow = blockIdx.x * 128, colBase = blockIdx.y * 128;
    int l4 = lane >> 2;
    int seg = lane & 3;

    int ar0 = blockRow + w * 16 + l4;
    int br0 = colBase + w * 16 + l4;
    const unsigned short* pA0 = A + (size_t)ar0 * KPAD + seg * 8;
    const unsigned short* pA1 = pA0 + (size_t)64 * KPAD;
    const unsigned short* pB0 = Wt + (size_t)br0 * KPAD + seg * 8;
    const unsigned short* pB1 = pB0 + (size_t)64 * KPAD;

    unsigned short* ldsA = As + w * 512;
    unsigned short* ldsB = Bs + w * 512;

    f32x4 acc[4][4] = {};
    int lr = lane & 15, lq = lane >> 4;

    for (int k0 = 0; k0 < KPAD; k0 += 32) {
        GLOAD_LDS16(pA0 + k0, ldsA);
        GLOAD_LDS16(pA1 + k0, ldsA + 2048);
        GLOAD_LDS16(pB0 + k0, ldsB);
        GLOAD_LDS16(pB1 + k0, ldsB + 2048);
        __syncthreads();
        bf16x8 a[4], b[4];
#pragma unroll
        for (int m = 0; m < 4; ++m)
            a[m] = *reinterpret_cast<const bf16x8*>(
                As + (wr * 64 + m * 16 + lr) * 32 + lq * 8);
#pragma unroll
        for (int n = 0; n < 4; ++n)
            b[n] = *reinterpret_cast<const bf16x8*>(
                Bs + (wc * 64 + n * 16 + lr) * 32 + lq * 8);
#pragma unroll
        for (int m = 0; m < 4; ++m)
#pragma unroll
            for (int n = 0; n < 4; ++n)
                acc[m][n] = __builtin_amdgcn_mfma_f32_16x16x32_bf16(
                    a[m], b[n], acc[m][n], 0, 0, 0);
        __syncthreads();
    }

    float bv[4];
#pragma unroll
    for (int n = 0; n < 4; ++n) bv[n] = bias[colBase + wc * 64 + n * 16 + lr];

#pragma unroll
    for (int m = 0; m < 4; ++m)
#pragma unroll
        for (int r = 0; r < 4; ++r) {
            int row = blockRow + wr * 64 + m * 16 + lq * 4 + r;
#pragma unroll
            for (int n = 0; n < 4; ++n) {
                int col = colBase + wc * 64 + n * 16 + lr;
                float v = acc[m][n][r] + bv[n];
                if (EPI == 2) {
                    outf[(size_t)row * 256 + col] =
                        v + resid[(size_t)row * 256 + col];
                } else {
                    Cb[(size_t)row * 256 + col] = f2b(fmaxf(v, 0.f));
                }
            }
        }
}

// node_in[nf][768] = [others(256 from f32), h(256 bf16), agg(256 f32)] bf16
__global__ void nodein_kernel(const float* __restrict__ others,
                              const unsigned short* __restrict__ hb,
                              const float* __restrict__ aggf,
                              unsigned short* __restrict__ node_in) {
    int idx = blockIdx.x * blockDim.x + threadIdx.x;
    int stride = gridDim.x * blockDim.x;
    const int total = TT * NN * 192;
    for (; idx < total; idx += stride) {
        int nf = idx / 192, c4 = (idx - nf * 192) * 4;
        ushort4 v;
        if (c4 < 256) {
            float4 o = *reinterpret_cast<const float4*>(others + (size_t)nf * 256 + c4);
            v.x = f2b(o.x); v.y = f2b(o.y); v.z = f2b(o.z); v.w = f2b(o.w);
        } else if (c4 < 512) {
            v = *reinterpret_cast<const ushort4*>(hb + (size_t)nf * 256 + (c4 - 256));
        } else {
            float4 a = *reinterpret_cast<const float4*>(aggf + (size_t)nf * 256 + (c4 - 512));
            v.x = f2b(a.x); v.y = f2b(a.y); v.z = f2b(a.z); v.w = f2b(a.w);
        }
        *reinterpret_cast<ushort4*>(node_in + (size_t)nf * 768 + c4) = v;
    }
}

__global__ void coordout_kernel(const float* __restrict__ x, const int* __restrict__ counts,
                                const float* __restrict__ csum, float* __restrict__ outc) {
    int idx = blockIdx.x * blockDim.x + threadIdx.x;
    if (idx >= TT * NN * 12) return;
    int n = (idx / 12) & (NN - 1);
    float cnt = (float)(counts[n] > 0 ? counts[n] : 1);
    outc[idx] = x[idx] + csum[idx] / cnt;
}

// ---------------- launch ----------------

extern "C" void kernel_launch(void* const* d_in, const int* in_sizes, int n_in,
                              void* d_out, int out_size, void* d_ws, size_t ws_size,
                              hipStream_t stream) {
    const float* x = (const float*)d_in[0];
    const float* h = (const float*)d_in[1];
    const float* others = (const float*)d_in[2];
    const float* We1 = (const float*)d_in[3];
    const float* be1 = (const float*)d_in[4];
    const float* We2 = (const float*)d_in[5];
    const float* be2 = (const float*)d_in[6];
    const float* Wn1 = (const float*)d_in[7];
    const float* bn1 = (const float*)d_in[8];
    const float* Wn2 = (const float*)d_in[9];
    const float* bn2 = (const float*)d_in[10];
    const float* Wc1 = (const float*)d_in[11];
    const float* bc1 = (const float*)d_in[12];
    const float* Wc2 = (const float*)d_in[13];
    const int* ei = (const int*)d_in[14];
    const int* rows = ei;
    const int* cols = ei + EE;

    char* wsb = (char*)d_ws;
    size_t off = 0;
    auto alloc = [&](size_t bytes) {
        void* p = wsb + off;
        off = (off + bytes + 255) & ~(size_t)255;
        return p;
    };
    const int TNH = TT * NN * HH;
    const int ME = TT * EE;  // 327680
    unsigned short* hb = (unsigned short*)alloc((size_t)TNH * 2);
    unsigned short* We1t = (unsigned short*)alloc(256 * 576 * 2);
    unsigned short* We2t = (unsigned short*)alloc(256 * 256 * 2);
    unsigned short* Wn1t = (unsigned short*)alloc(256 * 768 * 2);
    unsigned short* Wn2t = (unsigned short*)alloc(256 * 256 * 2);
    unsigned short* Wc1t = (unsigned short*)alloc(256 * 256 * 2);
    float* aggf = (float*)alloc((size_t)TT * NN * 256 * 4);  // contiguous zero region:
    float* csum = (float*)alloc((size_t)TT * NN * 12 * 4);   // aggf | csum | counts
    int* counts = (int*)alloc((size_t)NN * 4);
    unsigned short* Y1 = (unsigned short*)alloc((size_t)ME * 256 * 2);        // 168 MB
    unsigned short* radial32 = (unsigned short*)alloc((size_t)ME * 32 * 2);   // 21 MB
    float* cdiff = (float*)alloc((size_t)ME * 12 * 4);                        // 15.7 MB
    // Aliases (dead-after ordering on the single stream):
    unsigned short* node_in = Y1;              // Y1 dead after edge_tail_kernel
    unsigned short* Z = radial32;              // radial32 dead after gemm1_kernel
    (void)ws_size;

    // ---- setup ----
    cvt_bf16_kernel<<<2048, 256, 0, stream>>>(h, hb, TNH);
    transpose_w_kernel<<<576, 256, 0, stream>>>(We1, We1t, 528, 576);
    transpose_w_kernel<<<256, 256, 0, stream>>>(We2, We2t, 256, 256);
    transpose_w_kernel<<<768, 256, 0, stream>>>(Wn1, Wn1t, 768, 768);
    transpose_w_kernel<<<256, 256, 0, stream>>>(Wn2, Wn2t, 256, 256);
    transpose_w_kernel<<<256, 256, 0, stream>>>(Wc1, Wc1t, 256, 256);
    zero_f32_kernel<<<2048, 256, 0, stream>>>(
        aggf, TT * NN * 256 + TT * NN * 12 + NN);  // aggf+csum+counts
    count_kernel<<<EE / 256, 256, 0, stream>>>(rows, counts);

    float* houtf = (float*)d_out;
    float* coutf = (float*)d_out + (size_t)TT * NN * HH;

    // ---- edge pipeline, full batch ----
    radial_kernel<<<ME / 16, 256, 0, stream>>>(x, rows, cols, radial32, cdiff);
    gemm1_kernel<<<dim3(ME / 128, 2), 256, 0, stream>>>(
        hb, radial32, We1t, be1, rows, cols, Y1);
    edge_tail_kernel<<<ME / 128, 512, 0, stream>>>(
        Y1, We2t, be2, Wc1t, bc1, Wc2, rows, cdiff, aggf, csum);

    // ---- node pipeline ----
    nodein_kernel<<<2048, 256, 0, stream>>>(others, hb, aggf, node_in);
    node_gemm_kernel<0><<<dim3(TT * NN / 128, 2), 256, 0, stream>>>(
        node_in, Wn1t, bn1, Z, 768, nullptr, nullptr);
    node_gemm_kernel<2><<<dim3(TT * NN / 128, 2), 256, 0, stream>>>(
        Z, Wn2t, bn2, nullptr, 256, h, houtf);

    coordout_kernel<<<(TT * NN * 12 + 255) / 256, 256, 0, stream>>>(
        x, counts, csum, coutf);
}

// Round 6
// 524.301 us; speedup vs baseline: 1.4005x; 1.4005x over previous
//
#include <hip/hip_runtime.h>
#include <hip/hip_bf16.h>
#include <stdint.h>

// Problem constants (reference: T=10, N=2048, E=32768, H=256)
#define TT 10
#define NN 2048
#define EE 32768
#define HH 256

typedef short bf16x8 __attribute__((ext_vector_type(8)));
typedef float f32x4 __attribute__((ext_vector_type(4)));

__device__ __forceinline__ float b2f(unsigned short u) {
    unsigned int x = ((unsigned int)u) << 16;
    return __builtin_bit_cast(float, x);
}
__device__ __forceinline__ unsigned short f2b(float f) {
    unsigned int x = __builtin_bit_cast(unsigned int, f);
    unsigned int r = x + 0x7FFFu + ((x >> 16) & 1u);
    return (unsigned short)(r >> 16);
}

#define GLOAD_LDS16(g, l)                                                      \
    __builtin_amdgcn_global_load_lds(                                          \
        (const __attribute__((address_space(1))) void*)(g),                    \
        (__attribute__((address_space(3))) void*)(l), 16, 0, 0)

// ---------------- setup kernels ----------------

__global__ void cvt_bf16_kernel(const float* __restrict__ in,
                                unsigned short* __restrict__ out, int n) {
    int i = blockIdx.x * blockDim.x + threadIdx.x;
    int stride = gridDim.x * blockDim.x;
    for (; i < n; i += stride) out[i] = f2b(in[i]);
}

// W: [K][256] row-major -> Wt: [256][KPAD] bf16, zero-padded
__global__ void transpose_w_kernel(const float* __restrict__ W,
                                   unsigned short* __restrict__ Wt, int K, int KPAD) {
    int idx = blockIdx.x * blockDim.x + threadIdx.x;
    if (idx >= 256 * KPAD) return;
    int n = idx / KPAD, k = idx - n * KPAD;
    Wt[idx] = (k < K) ? f2b(W[k * 256 + n]) : (unsigned short)0;
}

__global__ void zero_f32_kernel(float* __restrict__ p, int n) {
    int i = blockIdx.x * blockDim.x + threadIdx.x;
    int stride = gridDim.x * blockDim.x;
    for (; i < n; i += stride) p[i] = 0.0f;
}

__global__ void count_kernel(const int* __restrict__ rows, int* __restrict__ counts) {
    int e = blockIdx.x * blockDim.x + threadIdx.x;
    if (e < EE) atomicAdd(&counts[rows[e]], 1);
}

// Exclusive scan of counts[0..2047] -> boff[0..2048]. One block, 256 threads.
__global__ __launch_bounds__(256) void scan_kernel(const int* __restrict__ counts,
                                                   int* __restrict__ boff) {
    __shared__ int part[256];
    int tid = threadIdx.x;
    int base = tid * 8;
    int local[8];
    int s = 0;
#pragma unroll
    for (int i = 0; i < 8; ++i) { local[i] = s; s += counts[base + i]; }
    part[tid] = s;
    __syncthreads();
    for (int offd = 1; offd < 256; offd <<= 1) {
        int v = (tid >= offd) ? part[tid - offd] : 0;
        __syncthreads();
        part[tid] += v;
        __syncthreads();
    }
    int pbase = (tid == 0) ? 0 : part[tid - 1];
#pragma unroll
    for (int i = 0; i < 8; ++i) boff[base + i] = pbase + local[i];
    if (tid == 255) boff[2048] = pbase + s;
}

// Scatter edges into row-sorted order: rs[pos]=row, cs[pos]=col.
__global__ void scatter_kernel(const int* __restrict__ rows, const int* __restrict__ cols,
                               const int* __restrict__ boff, int* __restrict__ cursor,
                               int* __restrict__ rs, int* __restrict__ cs) {
    int e = blockIdx.x * blockDim.x + threadIdx.x;
    if (e < EE) {
        int r = rows[e];
        int pos = boff[r] + atomicAdd(&cursor[r], 1);
        rs[pos] = r;
        cs[pos] = cols[e];
    }
}

// ---------------- radial (chunked, sorted order) ----------------
// 16 lanes per edge-instance el = tloc*EE+s: radial32[el][0..15]=normalized gram,
// [16..31]=0; cdiff[el][12] = x[t,rs[s]]-x[t,cs[s]].
__global__ __launch_bounds__(256) void radial_kernel(
    const float* __restrict__ x, const int* __restrict__ rs,
    const int* __restrict__ cs, unsigned short* __restrict__ radial32,
    float* __restrict__ cdiff, int tbase) {
    int tid = threadIdx.x;
    int el = blockIdx.x * 16 + (tid >> 4);
    int l16 = tid & 15;
    int s = el & (EE - 1);
    int t = tbase + (el >> 15);
    const float* xt = x + (size_t)t * NN * 12;
    int r = rs[s], c = cs[s];

    int j = l16 >> 2, kk = l16 & 3;
    float g = 0.f;
    for (int d = 0; d < 3; ++d) {
        float a = xt[r * 12 + j * 3 + d] - xt[c * 12 + j * 3 + d];
        float b = xt[r * 12 + kk * 3 + d] - xt[c * 12 + kk * 3 + d];
        g += a * b;
    }
    float ss = g * g;
    ss += __shfl_xor(ss, 1);
    ss += __shfl_xor(ss, 2);
    ss += __shfl_xor(ss, 4);
    ss += __shfl_xor(ss, 8);
    float denom = fmaxf(sqrtf(ss), 1e-12f);
    radial32[(size_t)el * 32 + l16] = f2b(g / denom);
    radial32[(size_t)el * 32 + 16 + l16] = 0;
    if (l16 < 12) {
        cdiff[(size_t)el * 12 + l16] = xt[r * 12 + l16] - xt[c * 12 + l16];
    }
}

// ---------------- GEMM1: Y1 = relu([h[rs]|h[cs]|radial] @ We1t^T + be1) ----------------
// m97 structure: 128x128 tile, BK=32, 4 waves (2x2), wave = 64x64 (4x4 frags).
__global__ __launch_bounds__(256) void gemm1_kernel(
    const unsigned short* __restrict__ hb, const unsigned short* __restrict__ radial32,
    const unsigned short* __restrict__ We1t, const float* __restrict__ be1,
    const int* __restrict__ rs, const int* __restrict__ cs,
    unsigned short* __restrict__ Y1, int tbase) {
    const int KPAD = 576;
    __shared__ unsigned short As[128 * 32];
    __shared__ unsigned short Bs[128 * 32];
    int tid = threadIdx.x;
    int lane = tid & 63, w = tid >> 6;
    int wr = w >> 1, wc = w & 1;
    int blockRow = blockIdx.x * 128, colBase = blockIdx.y * 128;
    int l4 = lane >> 2;
    int seg = lane & 3;

    int ar0 = blockRow + w * 16 + l4;
    int ar1 = ar0 + 64;
    int br0 = colBase + w * 16 + l4;
    int br1 = br0 + 64;

    const unsigned short* pB0 = We1t + (size_t)br0 * KPAD + seg * 8;
    const unsigned short* pB1 = We1t + (size_t)br1 * KPAD + seg * 8;

    int s0 = ar0 & (EE - 1), t0 = tbase + (ar0 >> 15);
    int s1 = ar1 & (EE - 1), t1 = tbase + (ar1 >> 15);
    const unsigned short* hr0 = hb + ((size_t)t0 * NN + rs[s0]) * 256 + seg * 8;
    const unsigned short* hc0 = hb + ((size_t)t0 * NN + cs[s0]) * 256 + seg * 8 - 256;
    const unsigned short* rd0 = radial32 + (size_t)ar0 * 32 + seg * 8 - 512;
    const unsigned short* hr1 = hb + ((size_t)t1 * NN + rs[s1]) * 256 + seg * 8;
    const unsigned short* hc1 = hb + ((size_t)t1 * NN + cs[s1]) * 256 + seg * 8 - 256;
    const unsigned short* rd1 = radial32 + (size_t)ar1 * 32 + seg * 8 - 512;

    unsigned short* ldsA = As + w * 512;
    unsigned short* ldsB = Bs + w * 512;

    f32x4 acc[4][4] = {};
    int lr = lane & 15, lq = lane >> 4;

    for (int k0 = 0; k0 < KPAD; k0 += 32) {
        const unsigned short* sa0 = (k0 < 256) ? hr0 + k0 : (k0 < 512) ? hc0 + k0 : rd0 + k0;
        const unsigned short* sa1 = (k0 < 256) ? hr1 + k0 : (k0 < 512) ? hc1 + k0 : rd1 + k0;
        GLOAD_LDS16(sa0, ldsA);
        GLOAD_LDS16(sa1, ldsA + 2048);
        GLOAD_LDS16(pB0 + k0, ldsB);
        GLOAD_LDS16(pB1 + k0, ldsB + 2048);
        __syncthreads();
        bf16x8 a[4], b[4];
#pragma unroll
        for (int m = 0; m < 4; ++m)
            a[m] = *reinterpret_cast<const bf16x8*>(
                As + (wr * 64 + m * 16 + lr) * 32 + lq * 8);
#pragma unroll
        for (int n = 0; n < 4; ++n)
            b[n] = *reinterpret_cast<const bf16x8*>(
                Bs + (wc * 64 + n * 16 + lr) * 32 + lq * 8);
#pragma unroll
        for (int m = 0; m < 4; ++m)
#pragma unroll
            for (int n = 0; n < 4; ++n)
                acc[m][n] = __builtin_amdgcn_mfma_f32_16x16x32_bf16(
                    a[m], b[n], acc[m][n], 0, 0, 0);
        __syncthreads();
    }

    float bv[4];
#pragma unroll
    for (int n = 0; n < 4; ++n) bv[n] = be1[colBase + wc * 64 + n * 16 + lr];

#pragma unroll
    for (int m = 0; m < 4; ++m)
#pragma unroll
        for (int r = 0; r < 4; ++r) {
            int row = blockRow + wr * 64 + m * 16 + lq * 4 + r;
#pragma unroll
            for (int n = 0; n < 4; ++n) {
                int col = colBase + wc * 64 + n * 16 + lr;
                Y1[(size_t)row * 256 + col] = f2b(fmaxf(acc[m][n][r] + bv[n], 0.f));
            }
        }
}

// ---------------- generic m97 GEMM ----------------
// EPI 0: relu -> bf16 store.
// EPI 2: f32 store outf = acc + bias + resid (no relu).
// EPI 3: relu -> dot Wc2[col], 16-lane reduce, atomicAdd m_e[row]. No store.
template<int EPI>
__global__ __launch_bounds__(256) void gemm_kernel(
    const unsigned short* __restrict__ A, const unsigned short* __restrict__ Wt,
    const float* __restrict__ bias, unsigned short* __restrict__ Cb, int KPAD,
    const float* __restrict__ resid, float* __restrict__ outf,
    const float* __restrict__ Wc2, float* __restrict__ m_e) {
    __shared__ unsigned short As[128 * 32];
    __shared__ unsigned short Bs[128 * 32];
    int tid = threadIdx.x;
    int lane = tid & 63, w = tid >> 6;
    int wr = w >> 1, wc = w & 1;
    int blockRow = blockIdx.x * 128, colBase = blockIdx.y * 128;
    int l4 = lane >> 2;
    int seg = lane & 3;

    int ar0 = blockRow + w * 16 + l4;
    int br0 = colBase + w * 16 + l4;
    const unsigned short* pA0 = A + (size_t)ar0 * KPAD + seg * 8;
    const unsigned short* pA1 = pA0 + (size_t)64 * KPAD;
    const unsigned short* pB0 = Wt + (size_t)br0 * KPAD + seg * 8;
    const unsigned short* pB1 = pB0 + (size_t)64 * KPAD;

    unsigned short* ldsA = As + w * 512;
    unsigned short* ldsB = Bs + w * 512;

    f32x4 acc[4][4] = {};
    int lr = lane & 15, lq = lane >> 4;

    for (int k0 = 0; k0 < KPAD; k0 += 32) {
        GLOAD_LDS16(pA0 + k0, ldsA);
        GLOAD_LDS16(pA1 + k0, ldsA + 2048);
        GLOAD_LDS16(pB0 + k0, ldsB);
        GLOAD_LDS16(pB1 + k0, ldsB + 2048);
        __syncthreads();
        bf16x8 a[4], b[4];
#pragma unroll
        for (int m = 0; m < 4; ++m)
            a[m] = *reinterpret_cast<const bf16x8*>(
                As + (wr * 64 + m * 16 + lr) * 32 + lq * 8);
#pragma unroll
        for (int n = 0; n < 4; ++n)
            b[n] = *reinterpret_cast<const bf16x8*>(
                Bs + (wc * 64 + n * 16 + lr) * 32 + lq * 8);
#pragma unroll
        for (int m = 0; m < 4; ++m)
#pragma unroll
            for (int n = 0; n < 4; ++n)
                acc[m][n] = __builtin_amdgcn_mfma_f32_16x16x32_bf16(
                    a[m], b[n], acc[m][n], 0, 0, 0);
        __syncthreads();
    }

    float bv[4], wv[4];
#pragma unroll
    for (int n = 0; n < 4; ++n) {
        int col = colBase + wc * 64 + n * 16 + lr;
        bv[n] = bias[col];
        if (EPI == 3) wv[n] = Wc2[col];
    }

#pragma unroll
    for (int m = 0; m < 4; ++m)
#pragma unroll
        for (int r = 0; r < 4; ++r) {
            int row = blockRow + wr * 64 + m * 16 + lq * 4 + r;
            if (EPI == 3) {
                float p = 0.f;
#pragma unroll
                for (int n = 0; n < 4; ++n)
                    p += fmaxf(acc[m][n][r] + bv[n], 0.f) * wv[n];
                p += __shfl_xor(p, 1);
                p += __shfl_xor(p, 2);
                p += __shfl_xor(p, 4);
                p += __shfl_xor(p, 8);
                if (lr == 0) atomicAdd(&m_e[row], p);
            } else {
#pragma unroll
                for (int n = 0; n < 4; ++n) {
                    int col = colBase + wc * 64 + n * 16 + lr;
                    float v = acc[m][n][r] + bv[n];
                    if (EPI == 2) {
                        outf[(size_t)row * 256 + col] =
                            v + resid[(size_t)row * 256 + col];
                    } else {
                        Cb[(size_t)row * 256 + col] = f2b(fmaxf(v, 0.f));
                    }
                }
            }
        }
}

// ---------------- CSR aggregation: zero atomics ----------------
// One block per (t_local, node): aggf[t,n,:] = sum of e_buf segment rows;
// csum[t,n,:] = sum cdiff*m_e over segment. Direct stores.
__global__ __launch_bounds__(256) void agg_csr_kernel(
    const unsigned short* __restrict__ e_buf, const int* __restrict__ boff,
    const float* __restrict__ cdiff, const float* __restrict__ m_e,
    float* __restrict__ aggf, float* __restrict__ csum, int tbase) {
    int b = blockIdx.x;
    int tloc = b >> 11, n = b & (NN - 1);
    int t = tbase + tloc;
    int s0 = boff[n], s1 = boff[n + 1];
    int tid = threadIdx.x;

    float acc = 0.f;
    const unsigned short* base = e_buf + ((size_t)tloc * EE) * 256 + tid;
    for (int s = s0; s < s1; ++s)
        acc += b2f(base[(size_t)s * 256]);
    aggf[((size_t)t * NN + n) * 256 + tid] = acc;

    if (tid < 12) {
        float csv = 0.f;
        for (int s = s0; s < s1; ++s)
            csv += cdiff[((size_t)tloc * EE + s) * 12 + tid] *
                   m_e[(size_t)tloc * EE + s];
        csum[((size_t)t * NN + n) * 12 + tid] = csv;
    }
}

// node_in[nf][768] = [others(256 f32), h(256 bf16), agg(256 f32)] as bf16
__global__ void nodein_kernel(const float* __restrict__ others,
                              const unsigned short* __restrict__ hb,
                              const float* __restrict__ aggf,
                              unsigned short* __restrict__ node_in) {
    int idx = blockIdx.x * blockDim.x + threadIdx.x;
    int stride = gridDim.x * blockDim.x;
    const int total = TT * NN * 192;
    for (; idx < total; idx += stride) {
        int nf = idx / 192, c4 = (idx - nf * 192) * 4;
        ushort4 v;
        if (c4 < 256) {
            float4 o = *reinterpret_cast<const float4*>(others + (size_t)nf * 256 + c4);
            v.x = f2b(o.x); v.y = f2b(o.y); v.z = f2b(o.z); v.w = f2b(o.w);
        } else if (c4 < 512) {
            v = *reinterpret_cast<const ushort4*>(hb + (size_t)nf * 256 + (c4 - 256));
        } else {
            float4 a = *reinterpret_cast<const float4*>(aggf + (size_t)nf * 256 + (c4 - 512));
            v.x = f2b(a.x); v.y = f2b(a.y); v.z = f2b(a.z); v.w = f2b(a.w);
        }
        *reinterpret_cast<ushort4*>(node_in + (size_t)nf * 768 + c4) = v;
    }
}

__global__ void coordout_kernel(const float* __restrict__ x, const int* __restrict__ counts,
                                const float* __restrict__ csum, float* __restrict__ outc) {
    int idx = blockIdx.x * blockDim.x + threadIdx.x;
    if (idx >= TT * NN * 12) return;
    int n = (idx / 12) & (NN - 1);
    float cnt = (float)(counts[n] > 0 ? counts[n] : 1);
    outc[idx] = x[idx] + csum[idx] / cnt;
}

// ---------------- launch ----------------

extern "C" void kernel_launch(void* const* d_in, const int* in_sizes, int n_in,
                              void* d_out, int out_size, void* d_ws, size_t ws_size,
                              hipStream_t stream) {
    const float* x = (const float*)d_in[0];
    const float* h = (const float*)d_in[1];
    const float* others = (const float*)d_in[2];
    const float* We1 = (const float*)d_in[3];
    const float* be1 = (const float*)d_in[4];
    const float* We2 = (const float*)d_in[5];
    const float* be2 = (const float*)d_in[6];
    const float* Wn1 = (const float*)d_in[7];
    const float* bn1 = (const float*)d_in[8];
    const float* Wn2 = (const float*)d_in[9];
    const float* bn2 = (const float*)d_in[10];
    const float* Wc1 = (const float*)d_in[11];
    const float* bc1 = (const float*)d_in[12];
    const float* Wc2 = (const float*)d_in[13];
    const int* ei = (const int*)d_in[14];
    const int* rows = ei;
    const int* cols = ei + EE;

    char* wsb = (char*)d_ws;
    size_t off = 0;
    auto alloc = [&](size_t bytes) {
        void* p = wsb + off;
        off = (off + bytes + 255) & ~(size_t)255;
        return p;
    };
    const int TNH = TT * NN * HH;
    // ---- fixed allocations ----
    unsigned short* hb = (unsigned short*)alloc((size_t)TNH * 2);
    unsigned short* We1t = (unsigned short*)alloc(256 * 576 * 2);
    unsigned short* We2t = (unsigned short*)alloc(256 * 256 * 2);
    unsigned short* Wn1t = (unsigned short*)alloc(256 * 768 * 2);
    unsigned short* Wn2t = (unsigned short*)alloc(256 * 256 * 2);
    unsigned short* Wc1t = (unsigned short*)alloc(256 * 256 * 2);
    float* aggf = (float*)alloc((size_t)TT * NN * 256 * 4);
    float* csum = (float*)alloc((size_t)TT * NN * 12 * 4);
    int* counts = (int*)alloc((size_t)2048 * 4);   // counts | cursor contiguous (zeroed together)
    int* cursor = (int*)alloc((size_t)2048 * 4);
    int* boff = (int*)alloc((size_t)2049 * 4);
    int* rs = (int*)alloc((size_t)EE * 4);
    int* cs = (int*)alloc((size_t)EE * 4);

    // ---- chunked allocations: pick largest TC in {10,5,2} that fits ----
    int TC = 2;
    {
        const int cand[3] = {10, 5, 2};
        for (int i = 0; i < 3; ++i) {
            size_t c = (size_t)cand[i] * EE;
            size_t need = 2 * (c * 256 * 2 + 256)   // Y1, e_buf
                        + (c * 32 * 2 + 256)        // radial32
                        + (c * 12 * 4 + 256)        // cdiff
                        + (c * 4 + 256);            // m_e
            if (off + need <= ws_size) { TC = cand[i]; break; }
        }
    }
    const int cM = TC * EE;
    unsigned short* Y1 = (unsigned short*)alloc((size_t)cM * 256 * 2);
    unsigned short* e_buf = (unsigned short*)alloc((size_t)cM * 256 * 2);
    unsigned short* radial32 = (unsigned short*)alloc((size_t)cM * 32 * 2);
    float* cdiff = (float*)alloc((size_t)cM * 12 * 4);
    float* m_e = (float*)alloc((size_t)cM * 4);
    // Aliases (dead-after ordering on the single stream); need cM >= 2*EE:
    unsigned short* node_in = Y1;   // Y1 dead after last chunk's gemm2
    unsigned short* Z = e_buf;      // e_buf dead after last chunk's agg_csr

    // ---- setup ----
    cvt_bf16_kernel<<<2048, 256, 0, stream>>>(h, hb, TNH);
    transpose_w_kernel<<<576, 256, 0, stream>>>(We1, We1t, 528, 576);
    transpose_w_kernel<<<256, 256, 0, stream>>>(We2, We2t, 256, 256);
    transpose_w_kernel<<<768, 256, 0, stream>>>(Wn1, Wn1t, 768, 768);
    transpose_w_kernel<<<256, 256, 0, stream>>>(Wn2, Wn2t, 256, 256);
    transpose_w_kernel<<<256, 256, 0, stream>>>(Wc1, Wc1t, 256, 256);
    zero_f32_kernel<<<16, 256, 0, stream>>>((float*)counts, 4096 + 256);  // counts+cursor(+pad)
    count_kernel<<<EE / 256, 256, 0, stream>>>(rows, counts);
    scan_kernel<<<1, 256, 0, stream>>>(counts, boff);
    scatter_kernel<<<EE / 256, 256, 0, stream>>>(rows, cols, boff, cursor, rs, cs);

    float* houtf = (float*)d_out;
    float* coutf = (float*)d_out + (size_t)TT * NN * HH;

    // ---- edge pipeline, chunked over timesteps ----
    for (int tbase = 0; tbase < TT; tbase += TC) {
        radial_kernel<<<cM / 16, 256, 0, stream>>>(x, rs, cs, radial32, cdiff, tbase);
        zero_f32_kernel<<<512, 256, 0, stream>>>(m_e, cM);

        gemm1_kernel<<<dim3(cM / 128, 2), 256, 0, stream>>>(
            hb, radial32, We1t, be1, rs, cs, Y1, tbase);
        gemm_kernel<0><<<dim3(cM / 128, 2), 256, 0, stream>>>(
            Y1, We2t, be2, e_buf, 256, nullptr, nullptr, nullptr, nullptr);
        gemm_kernel<3><<<dim3(cM / 128, 2), 256, 0, stream>>>(
            e_buf, Wc1t, bc1, nullptr, 256, nullptr, nullptr, Wc2, m_e);

        agg_csr_kernel<<<TC * NN, 256, 0, stream>>>(
            e_buf, boff, cdiff, m_e, aggf, csum, tbase);
    }

    // ---- node pipeline ----
    nodein_kernel<<<2048, 256, 0, stream>>>(others, hb, aggf, node_in);
    gemm_kernel<0><<<dim3(TT * NN / 128, 2), 256, 0, stream>>>(
        node_in, Wn1t, bn1, Z, 768, nullptr, nullptr, nullptr, nullptr);
    gemm_kernel<2><<<dim3(TT * NN / 128, 2), 256, 0, stream>>>(
        Z, Wn2t, bn2, nullptr, 256, h, houtf, nullptr, nullptr);

    coordout_kernel<<<(TT * NN * 12 + 255) / 256, 256, 0, stream>>>(
        x, counts, csum, coutf);
}

// Round 7
// 406.034 us; speedup vs baseline: 1.8084x; 1.2913x over previous
//
#include <hip/hip_runtime.h>
#include <hip/hip_bf16.h>
#include <stdint.h>

// Problem constants (reference: T=10, N=2048, E=32768, H=256)
#define TT 10
#define NN 2048
#define EE 32768
#define HH 256

typedef short bf16x8 __attribute__((ext_vector_type(8)));
typedef float f32x4 __attribute__((ext_vector_type(4)));

__device__ __forceinline__ float b2f(unsigned short u) {
    unsigned int x = ((unsigned int)u) << 16;
    return __builtin_bit_cast(float, x);
}
__device__ __forceinline__ unsigned short f2b(float f) {
    unsigned int x = __builtin_bit_cast(unsigned int, f);
    unsigned int r = x + 0x7FFFu + ((x >> 16) & 1u);
    return (unsigned short)(r >> 16);
}

#define GLOAD_LDS16(g, l)                                                      \
    __builtin_amdgcn_global_load_lds(                                          \
        (const __attribute__((address_space(1))) void*)(g),                    \
        (__attribute__((address_space(3))) void*)(l), 16, 0, 0)

// ---------------- setup kernels ----------------

__global__ void cvt_bf16_kernel(const float* __restrict__ in,
                                unsigned short* __restrict__ out, int n) {
    int i = blockIdx.x * blockDim.x + threadIdx.x;
    int stride = gridDim.x * blockDim.x;
    for (; i < n; i += stride) out[i] = f2b(in[i]);
}

// W: [K][256] row-major -> Wt: [256][KPAD] bf16, zero-padded
__global__ void transpose_w_kernel(const float* __restrict__ W,
                                   unsigned short* __restrict__ Wt, int K, int KPAD) {
    int idx = blockIdx.x * blockDim.x + threadIdx.x;
    if (idx >= 256 * KPAD) return;
    int n = idx / KPAD, k = idx - n * KPAD;
    Wt[idx] = (k < K) ? f2b(W[k * 256 + n]) : (unsigned short)0;
}

__global__ void zero_f32_kernel(float* __restrict__ p, int n) {
    int i = blockIdx.x * blockDim.x + threadIdx.x;
    int stride = gridDim.x * blockDim.x;
    for (; i < n; i += stride) p[i] = 0.0f;
}

__global__ void count_kernel(const int* __restrict__ rows, int* __restrict__ counts) {
    int e = blockIdx.x * blockDim.x + threadIdx.x;
    if (e < EE) atomicAdd(&counts[rows[e]], 1);
}

// Exclusive scan of counts[0..2047] -> boff[0..2048]. One block, 256 threads.
__global__ __launch_bounds__(256) void scan_kernel(const int* __restrict__ counts,
                                                   int* __restrict__ boff) {
    __shared__ int part[256];
    int tid = threadIdx.x;
    int base = tid * 8;
    int local[8];
    int s = 0;
#pragma unroll
    for (int i = 0; i < 8; ++i) { local[i] = s; s += counts[base + i]; }
    part[tid] = s;
    __syncthreads();
    for (int offd = 1; offd < 256; offd <<= 1) {
        int v = (tid >= offd) ? part[tid - offd] : 0;
        __syncthreads();
        part[tid] += v;
        __syncthreads();
    }
    int pbase = (tid == 0) ? 0 : part[tid - 1];
#pragma unroll
    for (int i = 0; i < 8; ++i) boff[base + i] = pbase + local[i];
    if (tid == 255) boff[2048] = pbase + s;
}

// Scatter edges into row-sorted order: rs[pos]=row, cs[pos]=col.
__global__ void scatter_kernel(const int* __restrict__ rows, const int* __restrict__ cols,
                               const int* __restrict__ boff, int* __restrict__ cursor,
                               int* __restrict__ rs, int* __restrict__ cs) {
    int e = blockIdx.x * blockDim.x + threadIdx.x;
    if (e < EE) {
        int r = rows[e];
        int pos = boff[r] + atomicAdd(&cursor[r], 1);
        rs[pos] = r;
        cs[pos] = cols[e];
    }
}

// ---------------- edge megakernel helpers (round-4 proven) ----------------

// Stage B tile [256][64] bf16 into Bs via global_load_lds; LDS stays linear,
// the XOR-swizzle is applied on the SOURCE kseg.
__device__ __forceinline__ void stageB(const unsigned short* __restrict__ Wt,
                                       int KPAD, int k0, int tid, int w,
                                       unsigned short* Bs) {
    int trow = tid >> 3;
    int sk8 = ((tid & 7) ^ (trow & 7)) * 8;
#pragma unroll
    for (int i = 0; i < 8; ++i) {
        int row = i * 32 + trow;
        GLOAD_LDS16(Wt + (size_t)row * KPAD + k0 + sk8, Bs + i * 2048 + w * 512);
    }
}

// One BK=64 MFMA step; A from As[64][64], B from Bs[256][64], both stored with
// per-row XOR swizzle; read with phys = col ^ ((row&7)<<3).
__device__ __forceinline__ void mfma_step(const unsigned short* As,
                                          const unsigned short* Bs,
                                          int w, int lr, int lq, f32x4 acc[4][4]) {
    int xs = (lr & 7) << 3;
#pragma unroll
    for (int kk = 0; kk < 64; kk += 32) {
        bf16x8 a[4], b[4];
        int pc = (kk + lq * 8) ^ xs;
#pragma unroll
        for (int m = 0; m < 4; ++m)
            a[m] = *reinterpret_cast<const bf16x8*>(As + (m * 16 + lr) * 64 + pc);
#pragma unroll
        for (int n = 0; n < 4; ++n)
            b[n] = *reinterpret_cast<const bf16x8*>(
                Bs + (w * 64 + n * 16 + lr) * 64 + pc);
#pragma unroll
        for (int m = 0; m < 4; ++m)
#pragma unroll
            for (int n = 0; n < 4; ++n)
                acc[m][n] = __builtin_amdgcn_mfma_f32_16x16x32_bf16(
                    a[m], b[n], acc[m][n], 0, 0, 0);
    }
}

// Same but A from Es[64][256] (swizzled, element phys = col ^ ((row&7)<<3)).
__device__ __forceinline__ void mfma_step_es(const unsigned short* Es,
                                             const unsigned short* Bs, int k0,
                                             int w, int lr, int lq, f32x4 acc[4][4]) {
    int xs = (lr & 7) << 3;
#pragma unroll
    for (int kk = 0; kk < 64; kk += 32) {
        bf16x8 a[4], b[4];
        int lcol = kk + lq * 8;
#pragma unroll
        for (int m = 0; m < 4; ++m)
            a[m] = *reinterpret_cast<const bf16x8*>(
                Es + (m * 16 + lr) * 256 + ((k0 + lcol) ^ xs));
#pragma unroll
        for (int n = 0; n < 4; ++n)
            b[n] = *reinterpret_cast<const bf16x8*>(
                Bs + (w * 64 + n * 16 + lr) * 64 + (lcol ^ xs));
#pragma unroll
        for (int m = 0; m < 4; ++m)
#pragma unroll
            for (int n = 0; n < 4; ++n)
                acc[m][n] = __builtin_amdgcn_mfma_f32_16x16x32_bf16(
                    a[m], b[n], acc[m][n], 0, 0, 0);
    }
}

// ---------------- edge megakernel (round-4 structure + CSR epilogues) ----------------
// Per block: 64 SORTED edge-instances. Phases:
//  0) radial + cdiff -> LDS (CDs, Rs)
//  1) E1 = relu([h[rs]|h[cs]|radial] @ We1t^T + be1)  K=576 -> Es
//  2) E2 = relu(E1 @ We2t^T + be2)                    K=256 -> Es
//  3) m  = relu(E2 @ Wc1t^T + bc1) . Wc2              K=256 -> Ms
//  epilogue: node-boundary-flush agg (Es) and csum (CDs*m) — low-contention atomics.
__global__ __launch_bounds__(256, 2) void edge_mega_kernel(
    const float* __restrict__ x, const unsigned short* __restrict__ hb,
    const unsigned short* __restrict__ We1t, const float* __restrict__ be1,
    const unsigned short* __restrict__ We2t, const float* __restrict__ be2,
    const unsigned short* __restrict__ Wc1t, const float* __restrict__ bc1,
    const float* __restrict__ Wc2,
    const int* __restrict__ rs, const int* __restrict__ cs,
    float* __restrict__ aggf, float* __restrict__ csum) {
    __shared__ unsigned short As[64 * 64];    // 8 KB
    __shared__ unsigned short Bs[256 * 64];   // 32 KB
    __shared__ unsigned short Es[64 * 256];   // 32 KB (swizzled)
    __shared__ float CDs[64][12];             // 3 KB
    __shared__ unsigned short Rs[64][16];     // 2 KB
    __shared__ float Ms[64][4];               // 1 KB

    int tid = threadIdx.x;
    int lane = tid & 63, w = tid >> 6;
    int lr = lane & 15, lq = lane >> 4;
    int blockRow = blockIdx.x * 64;
    int tt = blockRow >> 15;                  // uniform timestep per block
    int sb = blockRow & (EE - 1);             // base sorted-index for row 0

    // ---- phase 0: radial + cdiff for this block's 64 sorted edges ----
    if (tid < 64) {
        int s = sb + tid;
        int r = rs[s], c = cs[s];
        const float* xr = x + ((size_t)tt * NN + r) * 12;
        const float* xc = x + ((size_t)tt * NN + c) * 12;
        float cd[12];
#pragma unroll
        for (int i = 0; i < 12; ++i) {
            cd[i] = xr[i] - xc[i];
            CDs[tid][i] = cd[i];
        }
        float g[16], ss = 0.f;
#pragma unroll
        for (int j = 0; j < 4; ++j)
#pragma unroll
            for (int k = 0; k < 4; ++k) {
                float v = cd[j * 3] * cd[k * 3] + cd[j * 3 + 1] * cd[k * 3 + 1] +
                          cd[j * 3 + 2] * cd[k * 3 + 2];
                g[j * 4 + k] = v;
                ss += v * v;
            }
        float inv = 1.f / fmaxf(sqrtf(ss), 1e-12f);
#pragma unroll
        for (int i = 0; i < 16; ++i) Rs[tid][i] = f2b(g[i] * inv);
    }

    // gather source pointers for phase 1 A-staging
    int trow = tid >> 3;
    int sk8 = ((tid & 7) ^ (trow & 7)) * 8;
    const unsigned short *hr0, *hc0, *hr1, *hc1;
    {
        int s0 = sb + trow;
        int s1 = sb + 32 + trow;
        hr0 = hb + ((size_t)tt * NN + rs[s0]) * 256 + sk8;
        hc0 = hb + ((size_t)tt * NN + cs[s0]) * 256 + sk8 - 256;
        hr1 = hb + ((size_t)tt * NN + rs[s1]) * 256 + sk8;
        hc1 = hb + ((size_t)tt * NN + cs[s1]) * 256 + sk8 - 256;
    }

    __syncthreads();  // Rs/CDs ready

    f32x4 acc[4][4];
#pragma unroll
    for (int m = 0; m < 4; ++m)
#pragma unroll
        for (int n = 0; n < 4; ++n) acc[m][n] = (f32x4){0.f, 0.f, 0.f, 0.f};

    // ---- phase 1: K = 0..511 from h gathers, tail 512..575 from Rs ----
#pragma unroll 1
    for (int k0 = 0; k0 < 512; k0 += 64) {
        const unsigned short* s0 = (k0 < 256) ? hr0 + k0 : hc0 + k0;
        const unsigned short* s1 = (k0 < 256) ? hr1 + k0 : hc1 + k0;
        GLOAD_LDS16(s0, As + w * 512);
        GLOAD_LDS16(s1, As + 2048 + w * 512);
        stageB(We1t, 576, k0, tid, w, Bs);
        __syncthreads();
        mfma_step(As, Bs, w, lr, lq, acc);
        __syncthreads();
    }
    {   // radial tail step (k0 = 512): fill As from Rs via ds_write
#pragma unroll
        for (int j = 0; j < 2; ++j) {
            int row = j * 32 + trow;
            int lseg = (tid & 7) ^ (row & 7);
            bf16x8 v = {};
            if (lseg < 2) {
#pragma unroll
                for (int ii = 0; ii < 8; ++ii)
                    v[ii] = (short)Rs[row][lseg * 8 + ii];
            }
            *reinterpret_cast<bf16x8*>(As + row * 64 + (tid & 7) * 8) = v;
        }
        stageB(We1t, 576, 512, tid, w, Bs);
        __syncthreads();
        mfma_step(As, Bs, w, lr, lq, acc);
        __syncthreads();
    }
    {   // epilogue 1: relu + bias -> Es (swizzled bf16)
        float bv[4];
#pragma unroll
        for (int n = 0; n < 4; ++n) bv[n] = be1[w * 64 + n * 16 + lr];
#pragma unroll
        for (int m = 0; m < 4; ++m)
#pragma unroll
            for (int r = 0; r < 4; ++r) {
                int row = m * 16 + lq * 4 + r;
                int xsw = (row & 7) << 3;
#pragma unroll
                for (int n = 0; n < 4; ++n) {
                    int col = w * 64 + n * 16 + lr;
                    float v = fmaxf(acc[m][n][r] + bv[n], 0.f);
                    Es[row * 256 + (col ^ xsw)] = f2b(v);
                }
            }
    }
    __syncthreads();

    // ---- phase 2: E2 = relu(E1 @ We2t^T + be2) ----
#pragma unroll
    for (int m = 0; m < 4; ++m)
#pragma unroll
        for (int n = 0; n < 4; ++n) acc[m][n] = (f32x4){0.f, 0.f, 0.f, 0.f};
#pragma unroll 1
    for (int k0 = 0; k0 < 256; k0 += 64) {
        stageB(We2t, 256, k0, tid, w, Bs);
        __syncthreads();
        mfma_step_es(Es, Bs, k0, w, lr, lq, acc);
        __syncthreads();
    }
    {   // epilogue 2: overwrite Es with E2
        float bv[4];
#pragma unroll
        for (int n = 0; n < 4; ++n) bv[n] = be2[w * 64 + n * 16 + lr];
#pragma unroll
        for (int m = 0; m < 4; ++m)
#pragma unroll
            for (int r = 0; r < 4; ++r) {
                int row = m * 16 + lq * 4 + r;
                int xsw = (row & 7) << 3;
#pragma unroll
                for (int n = 0; n < 4; ++n) {
                    int col = w * 64 + n * 16 + lr;
                    float v = fmaxf(acc[m][n][r] + bv[n], 0.f);
                    Es[row * 256 + (col ^ xsw)] = f2b(v);
                }
            }
    }
    __syncthreads();

    // ---- phase 3: m = relu(E2 @ Wc1t^T + bc1) . Wc2 ----
#pragma unroll
    for (int m = 0; m < 4; ++m)
#pragma unroll
        for (int n = 0; n < 4; ++n) acc[m][n] = (f32x4){0.f, 0.f, 0.f, 0.f};
#pragma unroll 1
    for (int k0 = 0; k0 < 256; k0 += 64) {
        stageB(Wc1t, 256, k0, tid, w, Bs);
        __syncthreads();
        mfma_step_es(Es, Bs, k0, w, lr, lq, acc);
        __syncthreads();
    }
    {   // epilogue 3: per-row dot with Wc2, 16-lane reduce, cross-wave via Ms
        float bv[4], wv[4];
#pragma unroll
        for (int n = 0; n < 4; ++n) {
            int col = w * 64 + n * 16 + lr;
            bv[n] = bc1[col];
            wv[n] = Wc2[col];
        }
#pragma unroll
        for (int m = 0; m < 4; ++m)
#pragma unroll
            for (int r = 0; r < 4; ++r) {
                float p = 0.f;
#pragma unroll
                for (int n = 0; n < 4; ++n)
                    p += fmaxf(acc[m][n][r] + bv[n], 0.f) * wv[n];
                p += __shfl_xor(p, 1);
                p += __shfl_xor(p, 2);
                p += __shfl_xor(p, 4);
                p += __shfl_xor(p, 8);
                if (lr == 0) Ms[m * 16 + lq * 4 + r][w] = p;
            }
    }
    __syncthreads();

    if (tid < 64) {   // fold per-row m into Ms[.][0]
        Ms[tid][0] = Ms[tid][0] + Ms[tid][1] + Ms[tid][2] + Ms[tid][3];
    }
    __syncthreads();

    // ---- agg: rows sorted by node -> boundary-flush (low-contention atomics) ----
    {
        float accv = 0.f;
        for (int i = 0; i < 64; ++i) {
            int ncur = rs[sb + i];          // uniform scalar load
            accv += b2f(Es[i * 256 + (tid ^ ((i & 7) << 3))]);
            if (i == 63 || rs[sb + i + 1] != ncur) {
                atomicAdd(&aggf[((size_t)tt * NN + ncur) * 256 + tid], accv);
                accv = 0.f;
            }
        }
    }
    // ---- csum: same boundary-flush over CDs * m ----
    if (tid < 12) {
        float a = 0.f;
        for (int i = 0; i < 64; ++i) {
            int ncur = rs[sb + i];
            a += CDs[i][tid] * Ms[i][0];
            if (i == 63 || rs[sb + i + 1] != ncur) {
                atomicAdd(&csum[((size_t)tt * NN + ncur) * 12 + tid], a);
                a = 0.f;
            }
        }
    }
}

// ---------------- node GEMM (m97 128x128, BK=32) ----------------
// EPI 0: relu -> bf16 store.  EPI 2: f32 store outf = acc + bias + resid.
template<int EPI>
__global__ __launch_bounds__(256) void gemm_kernel(
    const unsigned short* __restrict__ A, const unsigned short* __restrict__ Wt,
    const float* __restrict__ bias, unsigned short* __restrict__ Cb, int KPAD,
    const float* __restrict__ resid, float* __restrict__ outf) {
    __shared__ unsigned short As[128 * 32];
    __shared__ unsigned short Bs[128 * 32];
    int tid = threadIdx.x;
    int lane = tid & 63, w = tid >> 6;
    int wr = w >> 1, wc = w & 1;
    int blockRow = blockIdx.x * 128, colBase = blockIdx.y * 128;
    int l4 = lane >> 2;
    int seg = lane & 3;

    int ar0 = blockRow + w * 16 + l4;
    int br0 = colBase + w * 16 + l4;
    const unsigned short* pA0 = A + (size_t)ar0 * KPAD + seg * 8;
    const unsigned short* pA1 = pA0 + (size_t)64 * KPAD;
    const unsigned short* pB0 = Wt + (size_t)br0 * KPAD + seg * 8;
    const unsigned short* pB1 = pB0 + (size_t)64 * KPAD;

    unsigned short* ldsA = As + w * 512;
    unsigned short* ldsB = Bs + w * 512;

    f32x4 acc[4][4] = {};
    int lr = lane & 15, lq = lane >> 4;

    for (int k0 = 0; k0 < KPAD; k0 += 32) {
        GLOAD_LDS16(pA0 + k0, ldsA);
        GLOAD_LDS16(pA1 + k0, ldsA + 2048);
        GLOAD_LDS16(pB0 + k0, ldsB);
        GLOAD_LDS16(pB1 + k0, ldsB + 2048);
        __syncthreads();
        bf16x8 a[4], b[4];
#pragma unroll
        for (int m = 0; m < 4; ++m)
            a[m] = *reinterpret_cast<const bf16x8*>(
                As + (wr * 64 + m * 16 + lr) * 32 + lq * 8);
#pragma unroll
        for (int n = 0; n < 4; ++n)
            b[n] = *reinterpret_cast<const bf16x8*>(
                Bs + (wc * 64 + n * 16 + lr) * 32 + lq * 8);
#pragma unroll
        for (int m = 0; m < 4; ++m)
#pragma unroll
            for (int n = 0; n < 4; ++n)
                acc[m][n] = __builtin_amdgcn_mfma_f32_16x16x32_bf16(
                    a[m], b[n], acc[m][n], 0, 0, 0);
        __syncthreads();
    }

    float bv[4];
#pragma unroll
    for (int n = 0; n < 4; ++n) bv[n] = bias[colBase + wc * 64 + n * 16 + lr];

#pragma unroll
    for (int m = 0; m < 4; ++m)
#pragma unroll
        for (int r = 0; r < 4; ++r) {
            int row = blockRow + wr * 64 + m * 16 + lq * 4 + r;
#pragma unroll
            for (int n = 0; n < 4; ++n) {
                int col = colBase + wc * 64 + n * 16 + lr;
                float v = acc[m][n][r] + bv[n];
                if (EPI == 2) {
                    outf[(size_t)row * 256 + col] =
                        v + resid[(size_t)row * 256 + col];
                } else {
                    Cb[(size_t)row * 256 + col] = f2b(fmaxf(v, 0.f));
                }
            }
        }
}

// node_in[nf][768] = [others(256 f32), h(256 bf16), agg(256 f32)] as bf16
__global__ void nodein_kernel(const float* __restrict__ others,
                              const unsigned short* __restrict__ hb,
                              const float* __restrict__ aggf,
                              unsigned short* __restrict__ node_in) {
    int idx = blockIdx.x * blockDim.x + threadIdx.x;
    int stride = gridDim.x * blockDim.x;
    const int total = TT * NN * 192;
    for (; idx < total; idx += stride) {
        int nf = idx / 192, c4 = (idx - nf * 192) * 4;
        ushort4 v;
        if (c4 < 256) {
            float4 o = *reinterpret_cast<const float4*>(others + (size_t)nf * 256 + c4);
            v.x = f2b(o.x); v.y = f2b(o.y); v.z = f2b(o.z); v.w = f2b(o.w);
        } else if (c4 < 512) {
            v = *reinterpret_cast<const ushort4*>(hb + (size_t)nf * 256 + (c4 - 256));
        } else {
            float4 a = *reinterpret_cast<const float4*>(aggf + (size_t)nf * 256 + (c4 - 512));
            v.x = f2b(a.x); v.y = f2b(a.y); v.z = f2b(a.z); v.w = f2b(a.w);
        }
        *reinterpret_cast<ushort4*>(node_in + (size_t)nf * 768 + c4) = v;
    }
}

__global__ void coordout_kernel(const float* __restrict__ x, const int* __restrict__ counts,
                                const float* __restrict__ csum, float* __restrict__ outc) {
    int idx = blockIdx.x * blockDim.x + threadIdx.x;
    if (idx >= TT * NN * 12) return;
    int n = (idx / 12) & (NN - 1);
    float cnt = (float)(counts[n] > 0 ? counts[n] : 1);
    outc[idx] = x[idx] + csum[idx] / cnt;
}

// ---------------- launch ----------------

extern "C" void kernel_launch(void* const* d_in, const int* in_sizes, int n_in,
                              void* d_out, int out_size, void* d_ws, size_t ws_size,
                              hipStream_t stream) {
    const float* x = (const float*)d_in[0];
    const float* h = (const float*)d_in[1];
    const float* others = (const float*)d_in[2];
    const float* We1 = (const float*)d_in[3];
    const float* be1 = (const float*)d_in[4];
    const float* We2 = (const float*)d_in[5];
    const float* be2 = (const float*)d_in[6];
    const float* Wn1 = (const float*)d_in[7];
    const float* bn1 = (const float*)d_in[8];
    const float* Wn2 = (const float*)d_in[9];
    const float* bn2 = (const float*)d_in[10];
    const float* Wc1 = (const float*)d_in[11];
    const float* bc1 = (const float*)d_in[12];
    const float* Wc2 = (const float*)d_in[13];
    const int* ei = (const int*)d_in[14];
    const int* rows = ei;
    const int* cols = ei + EE;

    char* wsb = (char*)d_ws;
    size_t off = 0;
    auto alloc = [&](size_t bytes) {
        void* p = wsb + off;
        off = (off + bytes + 255) & ~(size_t)255;
        return p;
    };
    const int TNH = TT * NN * HH;
    unsigned short* hb = (unsigned short*)alloc((size_t)TNH * 2);
    unsigned short* We1t = (unsigned short*)alloc(256 * 576 * 2);
    unsigned short* We2t = (unsigned short*)alloc(256 * 256 * 2);
    unsigned short* Wn1t = (unsigned short*)alloc(256 * 768 * 2);
    unsigned short* Wn2t = (unsigned short*)alloc(256 * 256 * 2);
    unsigned short* Wc1t = (unsigned short*)alloc(256 * 256 * 2);
    float* aggf = (float*)alloc((size_t)TT * NN * 256 * 4);  // contiguous zero region:
    float* csum = (float*)alloc((size_t)TT * NN * 12 * 4);   // aggf | csum
    int* counts = (int*)alloc((size_t)2048 * 4);   // counts | cursor (zeroed together)
    int* cursor = (int*)alloc((size_t)2048 * 4);
    int* boff = (int*)alloc((size_t)2049 * 4);
    int* rs = (int*)alloc((size_t)EE * 4);
    int* cs = (int*)alloc((size_t)EE * 4);
    unsigned short* node_in = (unsigned short*)alloc((size_t)TT * NN * 768 * 2);
    unsigned short* Z = (unsigned short*)alloc((size_t)TT * NN * 256 * 2);
    (void)ws_size;

    // ---- setup ----
    cvt_bf16_kernel<<<2048, 256, 0, stream>>>(h, hb, TNH);
    transpose_w_kernel<<<576, 256, 0, stream>>>(We1, We1t, 528, 576);
    transpose_w_kernel<<<256, 256, 0, stream>>>(We2, We2t, 256, 256);
    transpose_w_kernel<<<768, 256, 0, stream>>>(Wn1, Wn1t, 768, 768);
    transpose_w_kernel<<<256, 256, 0, stream>>>(Wn2, Wn2t, 256, 256);
    transpose_w_kernel<<<256, 256, 0, stream>>>(Wc1, Wc1t, 256, 256);
    zero_f32_kernel<<<16, 256, 0, stream>>>((float*)counts, 4096);  // counts+cursor
    count_kernel<<<EE / 256, 256, 0, stream>>>(rows, counts);
    scan_kernel<<<1, 256, 0, stream>>>(counts, boff);
    scatter_kernel<<<EE / 256, 256, 0, stream>>>(rows, cols, boff, cursor, rs, cs);
    zero_f32_kernel<<<2048, 256, 0, stream>>>(aggf, TT * NN * 256 + TT * NN * 12);

    float* houtf = (float*)d_out;
    float* coutf = (float*)d_out + (size_t)TT * NN * HH;

    // ---- fused edge pipeline: all T at once, sorted edges, CSR epilogues ----
    edge_mega_kernel<<<TT * EE / 64, 256, 0, stream>>>(
        x, hb, We1t, be1, We2t, be2, Wc1t, bc1, Wc2, rs, cs, aggf, csum);

    // ---- node pipeline ----
    nodein_kernel<<<2048, 256, 0, stream>>>(others, hb, aggf, node_in);
    gemm_kernel<0><<<dim3(TT * NN / 128, 2), 256, 0, stream>>>(
        node_in, Wn1t, bn1, Z, 768, nullptr, nullptr);
    gemm_kernel<2><<<dim3(TT * NN / 128, 2), 256, 0, stream>>>(
        Z, Wn2t, bn2, nullptr, 256, h, houtf);

    coordout_kernel<<<(TT * NN * 12 + 255) / 256, 256, 0, stream>>>(
        x, counts, csum, coutf);
}